// Round 13
// baseline (3050.624 us; speedup 1.0000x reference)
//
#include <hip/hip_runtime.h>
#include <math.h>

// ---------------- problem constants ----------------
#define NBAR   39
#define NPOPS  8
#define PSZ    32
#define TSTEPS 64
#define BATCH  64
#define CCH    64
#define NEUR   (NBAR*PSZ)      // 1248
#define NCONNS 37
#define TCH    8               // fallback time chunk (8 chunks of 8)

// connectivity (target-side, for kprepn)
constexpr int C_NSRC[NPOPS] = {5,5,6,6,4,3,6,2};
constexpr int C_OFF [NPOPS] = {0,5,10,16,22,26,29,35};

// source-grouped, NTP-padded tables: for source pop j, padded target count NTP
// (4 or 6 -> contiguous vector loads), target list (-1 = dead pad), conn k.
constexpr int G_NTP [NPOPS] = {4,6,6,6,4,4,6,6};
constexpr int G_CUMP[NPOPS] = {0,4,10,16,22,26,30,36};
constexpr int G_TGTP[42] = {0,1,4,-1,  0,1,2,3,5,-1,  0,1,2,3,6,-1,  0,1,2,3,6,-1,
                            0,1,4,6,  2,3,5,6,  2,3,4,6,7,-1,  2,3,4,5,6,7};
constexpr int G_KP  [42] = {0,5,22,-1, 1,6,10,16,26,-1, 2,7,11,17,29,-1, 3,8,12,18,30,-1,
                            4,9,23,31, 13,19,27,32, 14,20,24,33,35,-1, 15,21,25,28,34,36};
// region j: 1249 slots (f = n*32+c, slot 1248 = zeros) x 32 o x NTP floats
constexpr int G_OFFW2[NPOPS] = {0,159872,399680,639488,879296,1039168,1199040,1438848};
// total 1,678,656 floats = 6,714,624 B

// ---------------- workspace layouts (bytes) ----------------
// FALLBACK (chunked, TCH=8):
#define FB_XT     0           // f64 [T][B][NBAR][CCH]        81,788,928
#define FB_DRIVE  81788928    // f64 [TCH][B][NPOPS][NEUR]    40,894,464
#define FB_IDX    122683392   // i32 [T][B][NBAR][3]           1,916,928
#define FB_GW     124600320   // f32 grouped weights           6,714,624
#define FB_AGGT   131314944   // f32 [256][32]                    32,768
#define FB_CBIAS  131347712   // f64 [NPOPS][NEUR]                79,872
#define FB_ALRO   131427584   // f64 [NPOPS*NEUR][2]             159,744
#define FB_MEMG   131587328   // f64 [B][NPOPS][NEUR]          5,111,808
#define FB_BBRG   136699136
#define FB_ACCG   141810944
#define FB_STPROJ 146922752   //                                 638,976
#define FB_STSP   147561728   //                                  79,872
// end 147,641,600
// FULL (drive for all 64 t, single krec launch):
#define FU_XT     0           //                              81,788,928
#define FU_DRIVE  81788928    // f64 [64][B][NPOPS][NEUR]    327,155,712
#define FU_IDX    408944640   //                               1,916,928
#define FU_GW     410861568   //                               6,714,624
#define FU_AGGT   417576192   //                                  32,768
#define FU_CBIAS  417608960   //                                  79,872
#define FU_ALRO   417688832   //                                 159,744
#define FU_END    417848576ULL

// raw barrier: order LDS hand-off only; vmem stays in flight.
#define STEP_BAR() do { asm volatile("s_waitcnt lgkmcnt(0)" ::: "memory"); \
  __builtin_amdgcn_s_barrier(); asm volatile("" ::: "memory"); } while(0)

// ---------------- conv1d(2->64,k=3,s=2,p=1) -> xt f64 ----------------
__global__ __launch_bounds__(256) void kconv(const float* __restrict__ inp,
    const float* __restrict__ comp_w, const float* __restrict__ comp_b,
    double* __restrict__ xt)
{
  __shared__ float si[256];
  const int bn = blockIdx.x;
  const int b = bn / NBAR, n = bn % NBAR;
  const int tid = threadIdx.x;
  si[tid] = inp[bn*256 + tid];
  __syncthreads();
  const int c = tid & 63, tq = tid >> 6;
  double wv[6];
  #pragma unroll
  for (int u = 0; u < 6; ++u) wv[u] = (double)comp_w[c*6 + u];
  const double cb = (double)comp_b[c];
  for (int t = tq; t < TSTEPS; t += 4) {
    const int p0 = 2*t - 1;
    double acc = cb;
    if (p0 >= 0) acc += (double)si[p0]     * wv[0];
    acc             += (double)si[p0+1]    * wv[1];
    acc             += (double)si[p0+2]    * wv[2];
    if (p0 >= 0) acc += (double)si[128+p0] * wv[3];
    acc             += (double)si[128+p0+1]* wv[4];
    acc             += (double)si[128+p0+2]* wv[5];
    xt[((t*BATCH + b)*NBAR + n)*CCH + c] = acc;
  }
}

// ---------------- grouped-weight build: gw[j][f][o][NTP] (contiguous rows) ----------------
__global__ __launch_bounds__(256) void kprepw(const float* __restrict__ pop_w,
    float* __restrict__ gw)
{
  const int bx = blockIdx.x;          // j*40 + nn
  const int j = bx / 40, nn = bx % 40;
  const int NTP = G_NTP[j];
  float* reg = gw + G_OFFW2[j];
  if (nn < 39) {
    const int total = 32*32*NTP;      // c x o x u
    for (int e = threadIdx.x; e < total; e += 256) {
      const int c = e / (32*NTP), r = e % (32*NTP), o = r / NTP, u = r % NTP;
      const int kp = G_KP[G_CUMP[j] + u];
      reg[(nn*32 + c)*(32*NTP) + o*NTP + u] =
        (kp >= 0) ? pop_w[kp*39936 + nn*1024 + o*32 + c] : 0.0f;
    }
  } else {
    for (int e = threadIdx.x; e < 32*NTP; e += 256)
      reg[1248*(32*NTP) + e] = 0.0f;  // zero slot f=1248
  }
}

// ---------------- per-neuron constants + aggT transpose ----------------
__global__ __launch_bounds__(256) void kprepn(const float* __restrict__ th_b,
    const float* __restrict__ pop_b, const float* __restrict__ tau_adp,
    const float* __restrict__ tau_m, const float* __restrict__ agg_w,
    double* __restrict__ cbias, double* __restrict__ alro, float* __restrict__ aggT)
{
  const int e = blockIdx.x*256 + threadIdx.x;
  if (e < 8192) aggT[e] = agg_w[(e & 31)*256 + (e >> 5)];   // [m][o] <- [o][m]
  if (e >= NPOPS*NEUR) return;
  const int i = e / NEUR, r = e % NEUR;
  double cb = (double)th_b[e];
  const int no = C_NSRC[i], ofi = C_OFF[i];
  for (int jj = 0; jj < no; ++jj) cb += (double)pop_b[(ofi+jj)*NEUR + r];
  cbias[e] = cb;
  alro[2*e]   = exp(-1.0/(double)tau_m[e]);
  alro[2*e+1] = exp(-1.0/(double)tau_adp[e]);
}

// ---------------- similarity + top-3 (bank-conflict-free, padded) ----------------
__global__ __launch_bounds__(256) void ksim(const double* __restrict__ xt, int* __restrict__ idxg)
{
  __shared__ double sx[NBAR*65];        // stride 65 f64 -> conflict-free
  __shared__ double simL[NBAR*40];
  const int g = blockIdx.x;             // t*BATCH + b
  const int tid = threadIdx.x;
  const double* base = xt + (size_t)g*NBAR*CCH;
  for (int e = tid; e < NBAR*CCH; e += 256) sx[(e>>6)*65 + (e&63)] = base[e];
  __syncthreads();
  for (int p = tid; p < NBAR*NBAR; p += 256) {
    const int n = p / NBAR, m = p - n*NBAR;
    const double* xn = sx + n*65;
    const double* xm = sx + m*65;
    double acc = 0.0;
    #pragma unroll
    for (int c = 0; c < CCH; ++c) acc += xn[c]*xm[c];
    simL[n*40+m] = acc;
  }
  __syncthreads();
  if (tid < NBAR) {
    const double* row = simL + tid*40;
    double v0=-1e300, v1=-1e300, v2=-1e300; int i0=0, i1=0, i2=0;
    for (int m = 0; m < NBAR; ++m) {
      const double v = row[m];
      if      (v > v0) { v2=v1;i2=i1; v1=v0;i1=i0; v0=v;i0=m; }
      else if (v > v1) { v2=v1;i2=i1; v1=v; i1=m; }
      else if (v > v2) { v2=v; i2=m; }
    }
    int* op = idxg + (g*NBAR + tid)*3;
    op[0]=i0; op[1]=i1; op[2]=i2;
  }
}

// ---------------- drive precompute: register-tiled GEMM per barrel ----------------
__global__ __launch_bounds__(512) void kdrive(const double* __restrict__ xt,
    const float* __restrict__ th_w, const double* __restrict__ cbias,
    double* __restrict__ drive, int c0)
{
  __shared__ double sx[64*64];          // [row][c]   32 KB
  __shared__ float  sw[64*256];         // [c][pop*32+o]  64 KB
  const int n = blockIdx.x % NBAR, sl = blockIdx.x / NBAR;
  const int tid = threadIdx.x;
  for (int e = tid; e < 64*256; e += 512) {
    const int f = e >> 6, c = e & 63;   // f = pop*32+o
    sw[c*256 + f] = th_w[((f>>5)*NBAR + n)*2048 + (f&31)*64 + c];
  }
  for (int e = tid; e < 64*64; e += 512) {
    const int rr = e >> 6, cc = e & 63;
    const int g = sl*64 + rr, tt = g >> 6, bb = g & 63;
    sx[e] = xt[(((size_t)(c0+tt)*BATCH + bb)*NBAR + n)*CCH + cc];
  }
  __syncthreads();
  const int ot = tid & 31, rt = tid >> 5;
  double acc[4][8];
  #pragma unroll
  for (int k = 0; k < 8; ++k) {
    const double cb = cbias[k*NEUR + n*PSZ + ot];
    #pragma unroll
    for (int j = 0; j < 4; ++j) acc[j][k] = cb;
  }
  #pragma unroll 1
  for (int c = 0; c < 64; ++c) {
    double xv[4];
    #pragma unroll
    for (int j = 0; j < 4; ++j) xv[j] = sx[(rt*4+j)*64 + c];
    float wv[8];
    #pragma unroll
    for (int k = 0; k < 8; ++k) wv[k] = sw[c*256 + k*32 + ot];
    #pragma unroll
    for (int j = 0; j < 4; ++j)
      #pragma unroll
      for (int k = 0; k < 8; ++k)
        acc[j][k] += xv[j] * (double)wv[k];
  }
  #pragma unroll
  for (int j = 0; j < 4; ++j)
    #pragma unroll
    for (int k = 0; k < 8; ++k)
      drive[((size_t)(sl*64 + rt*4 + j)*NPOPS + k)*NEUR + n*PSZ + ot] = acc[j][k];
}

// scatter source-J spikes into acc regs: 4+4 bits per wait (single-buffered),
// NTP-contiguous rows -> per bit 1-3 merged vector loads instead of NT scalar.
template<int J>
__device__ __forceinline__ void scatJ(unsigned g0, unsigned g1, int n0, int n1v,
    const float* __restrict__ gw, int o, double* __restrict__ a0, double* __restrict__ a1)
{
  constexpr int NTP = G_NTP[J];
  constexpr int CU  = G_CUMP[J];
  const float* base = gw + G_OFFW2[J] + o*NTP;
  while (g0 | g1) {
    const float* p0[4]; const float* p1[4];
    #pragma unroll
    for (int u = 0; u < 4; ++u) {
      const int f0 = g0 ? (n0*32  + (__ffs(g0)-1)) : 1248; g0 &= g0-1;
      const int f1 = g1 ? (n1v*32 + (__ffs(g1)-1)) : 1248; g1 &= g1-1;
      p0[u] = base + (size_t)f0*(32*NTP);
      p1[u] = base + (size_t)f1*(32*NTP);
    }
    float w0[4][NTP], w1[4][NTP];
    #pragma unroll
    for (int u = 0; u < 4; ++u)
      #pragma unroll
      for (int v = 0; v < NTP; ++v) { w0[u][v] = p0[u][v]; w1[u][v] = p1[u][v]; }
    #pragma unroll
    for (int v = 0; v < NTP; ++v) {
      const int tg = G_TGTP[CU+v];
      if (tg >= 0) {
        a0[tg] += (((double)w0[0][v]+(double)w0[1][v]) + ((double)w0[2][v]+(double)w0[3][v]));
        a1[tg] += (((double)w1[0][v]+(double)w1[1][v]) + ((double)w1[2][v]+(double)w1[3][v]));
      }
    }
  }
}

// ---------------- recurrent core: 640 thr, 1 raw barrier per pop-step ----------------
// __launch_bounds__(640,3): VGPR cap ~170. bbr state in LDS (R12: -640 MB spill).
__global__ __launch_bounds__(640, 3) void krec(
    const double* __restrict__ drv, const int* __restrict__ idxg,
    const float* __restrict__ gw, const float* __restrict__ aggTg,
    const float* __restrict__ agg_b, const double* __restrict__ alro,
    double* __restrict__ memG, double* __restrict__ bbrG,
    double* __restrict__ accG, double* __restrict__ stProj, unsigned* __restrict__ stSp,
    float* __restrict__ hOut, float* __restrict__ mOut, int t0, int nT)
{
  __shared__ double   proj[2][NBAR*PSZ];  // 19,968 B ping-pong
  __shared__ float    aggT[256*PSZ];      // 32,768 B
  __shared__ unsigned spM[NPOPS*40];      //  1,280 B
  __shared__ double   bbrL[NPOPS*40*PSZ]; // 81,920 B  ([i][40][32], row 39 dummy)
  const int b = blockIdx.x, tid = threadIdx.x;
  const int o = tid & 31, s = tid >> 5;   // 20 half-wave slots
  const int n0 = s, n1 = s + 20;
  const bool h1 = (n1 < NBAR);            // s < 19
  const int n1v = h1 ? n1 : n0;

  for (int e = tid; e < 256*PSZ; e += 640) aggT[e] = aggTg[e];

  double mem0[NPOPS], mem1[NPOPS], acc0[NPOPS], acc1[NPOPS];
  const size_t mbase = (size_t)b*NPOPS*NEUR;
  if (t0 == 0) {
    #pragma unroll
    for (int i = 0; i < NPOPS; ++i) {
      mem0[i]=0.0; mem1[i]=0.0; acc0[i]=0.0; acc1[i]=0.0;
    }
    for (int e = tid; e < NPOPS*40*PSZ; e += 640) bbrL[e] = 0.0;
    for (int e = tid; e < NBAR*PSZ; e += 640) proj[0][e] = 0.0;
    for (int e = tid; e < NPOPS*40; e += 640) spM[e] = 0u;
  } else {
    #pragma unroll
    for (int i = 0; i < NPOPS; ++i) {
      const size_t eA = mbase + i*NEUR + n0*PSZ + o;
      const size_t eB = mbase + i*NEUR + n1v*PSZ + o;
      mem0[i] = memG[eA]; acc0[i] = accG[eA];
      mem1[i] = h1 ? memG[eB] : 0.0;
      acc1[i] = h1 ? accG[eB] : 0.0;
    }
    for (int e = tid; e < NPOPS*NEUR; e += 640)
      bbrL[(e/NEUR)*1280 + (e%NEUR)] = bbrG[mbase + e];
    if (tid < NPOPS*PSZ) bbrL[(tid>>5)*1280 + 39*PSZ + (tid&31)] = 0.0; // dummy row
    for (int e = tid; e < NBAR*PSZ; e += 640) proj[0][e] = stProj[b*NEUR + e];
    for (int e = tid; e < NPOPS*40; e += 640)
      spM[e] = ((e % 40) < NBAR) ? stSp[b*NPOPS*NBAR + (e/40)*NBAR + (e%40)] : 0u;
  }
  __syncthreads();
  const double aggBo = (double)agg_b[o];
  int rb = 0;

  #pragma unroll 1
  for (int tt = 0; tt < nT; ++tt) {
    const int t = t0 + tt;
    const double* drvT = drv + ((size_t)(tt*BATCH + b))*NPOPS*NEUR;
    #pragma unroll
    for (int i = 0; i < NPOPS; ++i) {
      acc0[i] += drvT[i*NEUR + n0*PSZ + o];
      if (h1) acc1[i] += drvT[i*NEUR + n1*PSZ + o];
    }
    int ia0[3], ia1[3];
    { const int* ip = idxg + ((t*BATCH+b)*NBAR + n0)*3; ia0[0]=ip[0]; ia0[1]=ip[1]; ia0[2]=ip[2]; }
    if (h1) { const int* ip = idxg + ((t*BATCH+b)*NBAR + n1)*3; ia1[0]=ip[0]; ia1[1]=ip[1]; ia1[2]=ip[2]; }
    else    { ia1[0]=ia1[1]=ia1[2]=0; }

    #pragma unroll
    for (int i = 0; i < NPOPS; ++i) {
      const int eA = i*NEUR + n0*PSZ + o;
      const int eB = i*NEUR + n1v*PSZ + o;
      const double al0 = alro[2*eA], ro0 = alro[2*eA+1];
      const double al1 = alro[2*eB], ro1 = alro[2*eB+1];
      const double* prj = proj[rb];
      double*       prw = proj[rb^1];
      const int bix0 = i*1280 + n0*PSZ + o;
      const int bix1 = i*1280 + n1*PSZ + o;   // row 39 dummy for s=19

      // ---- phase 1: fold acc + neighbor agg (reads prj)
      double cur0 = acc0[i]; acc0[i] = 0.0;
      double cur1 = acc1[i]; acc1[i] = 0.0;
      if (t > 0) {
        cur0 += 0.1*((prj[ia0[0]*PSZ+o]+prj[ia0[1]*PSZ+o]+prj[ia0[2]*PSZ+o])/3.0 + aggBo);
        if (h1)
          cur1 += 0.1*((prj[ia1[0]*PSZ+o]+prj[ia1[1]*PSZ+o]+prj[ia1[2]*PSZ+o])/3.0 + aggBo);
      }

      // ---- phase 2: neuron update, ballot, outputs, proj copy+delta (writes prw)
      unsigned newM0, newM1;
      {
        const unsigned oldM = spM[i*40 + n0];
        const double sOld = (double)((oldM >> o) & 1u);
        const double bn  = ro0*bbrL[bix0] + (1.0-ro0)*sOld;
        const double Bth = 0.02 + 1.8*bn;
        const double mN  = mem0[i]*al0 + (1.0-al0)*cur0;
        const int spk = (mN - Bth) > 0.0;
        mem0[i] = mN - Bth*(double)spk;
        bbrL[bix0] = bn;
        const int ob = ((b*TSTEPS + t)*NBAR + n0)*256 + i*PSZ + o;
        hOut[ob] = (float)spk;
        mOut[ob] = (float)mN;
        const unsigned long long bal = __ballot(spk);
        newM0 = (tid & 32) ? (unsigned)(bal >> 32) : (unsigned)(bal & 0xffffffffULL);
        if (o == 0) spM[i*40 + n0] = newM0;
        unsigned diff = newM0 ^ oldM;
        double pv = prj[n0*PSZ + o];
        while (diff) {
          unsigned d = diff;
          const int cA = __ffs(d)-1; d &= d-1;
          const bool hB = d!=0; const int cB = hB ? __ffs(d)-1 : cA; d &= d-1;
          const bool hC = d!=0; const int cC = hC ? __ffs(d)-1 : cA; d &= d-1;
          const bool hD = d!=0; const int cD = hD ? __ffs(d)-1 : cA; d &= d-1;
          diff = d;
          const double wA = (double)aggT[(i*PSZ+cA)*PSZ+o];
          const double wB = (double)aggT[(i*PSZ+cB)*PSZ+o];
          const double wC = (double)aggT[(i*PSZ+cC)*PSZ+o];
          const double wD = (double)aggT[(i*PSZ+cD)*PSZ+o];
          pv += ((newM0>>cA)&1u) ? wA : -wA;
          pv += hB ? (((newM0>>cB)&1u) ? wB : -wB) : 0.0;
          pv += hC ? (((newM0>>cC)&1u) ? wC : -wC) : 0.0;
          pv += hD ? (((newM0>>cD)&1u) ? wD : -wD) : 0.0;
        }
        prw[n0*PSZ + o] = pv;
      }
      {
        const unsigned oldM = h1 ? spM[i*40 + n1] : 0u;
        const double sOld = (double)((oldM >> o) & 1u);
        const double bn  = ro1*bbrL[bix1] + (1.0-ro1)*sOld;
        const double Bth = 0.02 + 1.8*bn;
        const double mN  = mem1[i]*al1 + (1.0-al1)*cur1;
        const int spk = (mN - Bth) > 0.0;
        mem1[i] = mN - Bth*(double)spk;
        bbrL[bix1] = bn;
        if (h1) {
          const int ob = ((b*TSTEPS + t)*NBAR + n1)*256 + i*PSZ + o;
          hOut[ob] = (float)spk;
          mOut[ob] = (float)mN;
        }
        const unsigned long long bal = __ballot(h1 && spk);
        newM1 = (tid & 32) ? (unsigned)(bal >> 32) : (unsigned)(bal & 0xffffffffULL);
        if (h1) {
          if (o == 0) spM[i*40 + n1] = newM1;
          unsigned diff = newM1 ^ oldM;
          double pv = prj[n1*PSZ + o];
          while (diff) {
            unsigned d = diff;
            const int cA = __ffs(d)-1; d &= d-1;
            const bool hB = d!=0; const int cB = hB ? __ffs(d)-1 : cA; d &= d-1;
            const bool hC = d!=0; const int cC = hC ? __ffs(d)-1 : cA; d &= d-1;
            const bool hD = d!=0; const int cD = hD ? __ffs(d)-1 : cA; d &= d-1;
            diff = d;
            const double wA = (double)aggT[(i*PSZ+cA)*PSZ+o];
            const double wB = (double)aggT[(i*PSZ+cB)*PSZ+o];
            const double wC = (double)aggT[(i*PSZ+cC)*PSZ+o];
            const double wD = (double)aggT[(i*PSZ+cD)*PSZ+o];
            pv += ((newM1>>cA)&1u) ? wA : -wA;
            pv += hB ? (((newM1>>cB)&1u) ? wB : -wB) : 0.0;
            pv += hC ? (((newM1>>cC)&1u) ? wC : -wC) : 0.0;
            pv += hD ? (((newM1>>cD)&1u) ? wD : -wD) : 0.0;
          }
          prw[n1*PSZ + o] = pv;
        }
      }

      // ---- scatter source-i spikes into acc regs (loads drain lazily, next steps)
      const unsigned g0 = newM0, g1 = h1 ? newM1 : 0u;
      if      (i == 0) scatJ<0>(g0, g1, n0, n1v, gw, o, acc0, acc1);
      else if (i == 1) scatJ<1>(g0, g1, n0, n1v, gw, o, acc0, acc1);
      else if (i == 2) scatJ<2>(g0, g1, n0, n1v, gw, o, acc0, acc1);
      else if (i == 3) scatJ<3>(g0, g1, n0, n1v, gw, o, acc0, acc1);
      else if (i == 4) scatJ<4>(g0, g1, n0, n1v, gw, o, acc0, acc1);
      else if (i == 5) scatJ<5>(g0, g1, n0, n1v, gw, o, acc0, acc1);
      else if (i == 6) scatJ<6>(g0, g1, n0, n1v, gw, o, acc0, acc1);
      else             scatJ<7>(g0, g1, n0, n1v, gw, o, acc0, acc1);

      STEP_BAR();      // lgkmcnt(0) + s_barrier only; vmem stays in flight
      rb ^= 1;
    }
  }

  // persist chunk state only when another chunk follows
  if (t0 + nT < TSTEPS) {
    #pragma unroll
    for (int i = 0; i < NPOPS; ++i) {
      const size_t eA = mbase + i*NEUR + n0*PSZ + o;
      memG[eA] = mem0[i]; accG[eA] = acc0[i];
      if (h1) {
        const size_t eB = mbase + i*NEUR + n1*PSZ + o;
        memG[eB] = mem1[i]; accG[eB] = acc1[i];
      }
    }
    for (int e = tid; e < NPOPS*NEUR; e += 640)
      bbrG[mbase + e] = bbrL[(e/NEUR)*1280 + (e%NEUR)];
    for (int e = tid; e < NEUR; e += 640) stProj[b*NEUR + e] = proj[rb][e];
    for (int e = tid; e < NPOPS*NBAR; e += 640)
      stSp[b*NPOPS*NBAR + e] = spM[(e/NBAR)*40 + (e%NBAR)];
  }
}

// ---------------- readout ----------------
__global__ __launch_bounds__(256) void kread(const float* __restrict__ hBase,
    const float* __restrict__ ro_w, const float* __restrict__ ro_b, float* __restrict__ outp)
{
  __shared__ double part[2][128];
  __shared__ double meanv[128];
  __shared__ double lg[36];
  const int b = blockIdx.x, tid = threadIdx.x;
  const int d = tid & 127, half = tid >> 7;
  double acc = 0.0;
  for (int r = half*1248; r < half*1248 + 1248; ++r)
    acc += (double)hBase[((size_t)b*2496 + r)*256 + 128 + d];
  part[half][d] = acc;
  __syncthreads();
  if (tid < 128) meanv[tid] = (part[0][tid] + part[1][tid]) / 2496.0;
  __syncthreads();
  if (tid < 36) {
    double a = (double)ro_b[tid];
    for (int e = 0; e < 128; ++e) a += meanv[e]*(double)ro_w[tid*128 + e];
    lg[tid] = a;
  }
  __syncthreads();
  if (tid == 0) {
    double mx = lg[0];
    for (int dd = 1; dd < 36; ++dd) mx = fmax(mx, lg[dd]);
    double ex[36]; double sum = 0.0;
    for (int dd = 0; dd < 36; ++dd) { ex[dd] = exp(lg[dd]-mx); sum += ex[dd]; }
    for (int dd = 0; dd < 36; ++dd) outp[b*36 + dd] = (float)(ex[dd]/sum);
  }
}

// ---------------- launcher ----------------
extern "C" void kernel_launch(void* const* d_in, const int* in_sizes, int n_in,
                              void* d_out, int out_size, void* d_ws, size_t ws_size,
                              hipStream_t stream)
{
  const float* inp     = (const float*)d_in[0];
  const float* comp_w  = (const float*)d_in[1];
  const float* comp_b  = (const float*)d_in[2];
  const float* th_w    = (const float*)d_in[3];
  const float* th_b    = (const float*)d_in[4];
  const float* pop_w   = (const float*)d_in[5];
  const float* pop_b   = (const float*)d_in[6];
  const float* tau_adp = (const float*)d_in[7];
  const float* tau_m   = (const float*)d_in[8];
  const float* agg_w   = (const float*)d_in[9];
  const float* agg_b   = (const float*)d_in[10];
  const float* ro_w    = (const float*)d_in[11];
  const float* ro_b    = (const float*)d_in[12];

  char* ws = (char*)d_ws;
  float* outp = (float*)d_out;                 // (64,36) softmax
  float* hOut = outp + 64*36;                  // (64,64,39,256)
  float* mOut = hOut + 64*64*39*256;           // (64,64,39,256)

  const bool full = (ws_size >= FU_END);

  if (full) {
    // -------- full path: drive for all 64 t, single krec launch --------
    double*   xt     = (double*)  (ws + FU_XT);
    double*   drive  = (double*)  (ws + FU_DRIVE);
    int*      idxg   = (int*)     (ws + FU_IDX);
    float*    gw     = (float*)   (ws + FU_GW);
    float*    aggT   = (float*)   (ws + FU_AGGT);
    double*   cbias  = (double*)  (ws + FU_CBIAS);
    double*   alro   = (double*)  (ws + FU_ALRO);
    double*   dummy  = (double*)  (ws + FU_XT);    // state ptrs never touched (t0=0, nT=64)
    unsigned* dummyu = (unsigned*)(ws + FU_XT);

    kconv <<<BATCH*NBAR, 256, 0, stream>>>(inp, comp_w, comp_b, xt);
    kprepw<<<NPOPS*40, 256, 0, stream>>>(pop_w, gw);
    kprepn<<<39, 256, 0, stream>>>(th_b, pop_b, tau_adp, tau_m, agg_w, cbias, alro, aggT);
    ksim  <<<TSTEPS*BATCH, 256, 0, stream>>>(xt, idxg);
    kdrive<<<NBAR*64, 512, 0, stream>>>(xt, th_w, cbias, drive, 0);
    krec  <<<BATCH, 640, 0, stream>>>(drive, idxg, gw, aggT, agg_b, alro,
                                      dummy, dummy, dummy, dummy, dummyu,
                                      hOut, mOut, 0, TSTEPS);
    kread <<<BATCH, 256, 0, stream>>>(hOut, ro_w, ro_b, outp);
  } else {
    // -------- fallback: chunked path --------
    double*   xt     = (double*)  (ws + FB_XT);
    double*   drive  = (double*)  (ws + FB_DRIVE);
    int*      idxg   = (int*)     (ws + FB_IDX);
    float*    gw     = (float*)   (ws + FB_GW);
    float*    aggT   = (float*)   (ws + FB_AGGT);
    double*   cbias  = (double*)  (ws + FB_CBIAS);
    double*   alro   = (double*)  (ws + FB_ALRO);
    double*   memG   = (double*)  (ws + FB_MEMG);
    double*   bbrG   = (double*)  (ws + FB_BBRG);
    double*   accG   = (double*)  (ws + FB_ACCG);
    double*   stProj = (double*)  (ws + FB_STPROJ);
    unsigned* stSp   = (unsigned*)(ws + FB_STSP);

    kconv <<<BATCH*NBAR, 256, 0, stream>>>(inp, comp_w, comp_b, xt);
    kprepw<<<NPOPS*40, 256, 0, stream>>>(pop_w, gw);
    kprepn<<<39, 256, 0, stream>>>(th_b, pop_b, tau_adp, tau_m, agg_w, cbias, alro, aggT);
    ksim  <<<TSTEPS*BATCH, 256, 0, stream>>>(xt, idxg);
    for (int c0 = 0; c0 < TSTEPS; c0 += TCH) {
      kdrive<<<NBAR*8, 512, 0, stream>>>(xt, th_w, cbias, drive, c0);
      krec  <<<BATCH, 640, 0, stream>>>(drive, idxg, gw, aggT, agg_b, alro,
                                        memG, bbrG, accG, stProj, stSp,
                                        hOut, mOut, c0, TCH);
    }
    kread <<<BATCH, 256, 0, stream>>>(hOut, ro_w, ro_b, outp);
  }
}

// Round 14
// 2669.001 us; speedup vs baseline: 1.1430x; 1.1430x over previous
//
#include <hip/hip_runtime.h>
#include <math.h>

// ---------------- problem constants ----------------
#define NBAR   39
#define NPOPS  8
#define PSZ    32
#define TSTEPS 64
#define BATCH  64
#define CCH    64
#define NEUR   (NBAR*PSZ)      // 1248
#define NCONNS 37
#define TCH    8               // fallback time chunk (8 chunks of 8)

// connectivity
constexpr int C_NSRC[NPOPS] = {5,5,6,6,4,3,6,2};
constexpr int C_OFF [NPOPS] = {0,5,10,16,22,26,29,35};

// source-grouped tables: for source pop j, its target pops (ascending) and the
// connection index k supplying weights pop_w[k] for (source j -> target i).
constexpr int G_NT  [NPOPS] = {3,5,5,5,4,4,5,6};
constexpr int G_CUM [NPOPS] = {0,3,8,13,18,22,26,31};
constexpr int G_TGT [NCONNS] = {0,1,4,  0,1,2,3,5,  0,1,2,3,6,  0,1,2,3,6,
                                0,1,4,6,  2,3,5,6,  2,3,4,6,7,  2,3,4,5,6,7};
constexpr int G_K   [NCONNS] = {0,5,22, 1,6,10,16,26, 2,7,11,17,29, 3,8,12,18,30,
                                4,9,23,31, 13,19,27,32, 14,20,24,33,35, 15,21,25,28,34,36};
// region j: 1249 flat (n*32+c) slots (incl. zero-pad slot 1248) x NT x 32 floats
constexpr int G_OFFW[NPOPS] = {0,119904,319744,519584,719424,879296,1039168,1239008};

// ---------------- workspace layouts (bytes) ----------------
// FALLBACK (chunked, TCH=8):
#define FB_XT     0           // f64 [T][B][NBAR][CCH]        81,788,928
#define FB_DRIVE  81788928    // f64 [TCH][B][NPOPS][NEUR]    40,894,464
#define FB_IDX    122683392   // i32 [T][B][NBAR][3]           1,916,928
#define FB_GW     124600320   // f32 grouped weights           5,915,264
#define FB_AGGT   130515584   // f32 [256][32]                    32,768
#define FB_CBIAS  130548352   // f64 [NPOPS][NEUR]                79,872
#define FB_ALRO   130628224   // f64 [NPOPS*NEUR][2]             159,744
#define FB_MEMG   130787968   // f64 [B][NPOPS][NEUR]          5,111,808
#define FB_BBRG   135899776
#define FB_ACCG   141011584
#define FB_STPROJ 146123392
#define FB_STSP   146762368
// FULL (drive for all 64 t, single krec launch):
#define FU_XT     0           //                              81,788,928
#define FU_DRIVE  81788928    // f64 [64][B][NPOPS][NEUR]    327,155,712
#define FU_IDX    408944640   //                               1,916,928
#define FU_GW     410861568   //                               5,915,264
#define FU_AGGT   416776832   //                                  32,768
#define FU_CBIAS  416809600   //                                  79,872
#define FU_ALRO   416889472   //                                 159,744
#define FU_END    417049216ULL

// raw barrier: order LDS hand-off only; do NOT drain vmem (scatter loads /
// output stores have register-only / no consumers across the barrier).
#define STEP_BAR() do { asm volatile("s_waitcnt lgkmcnt(0)" ::: "memory"); \
  __builtin_amdgcn_s_barrier(); asm volatile("" ::: "memory"); } while(0)

// ---------------- conv1d(2->64,k=3,s=2,p=1) -> xt f64 ----------------
__global__ __launch_bounds__(256) void kconv(const float* __restrict__ inp,
    const float* __restrict__ comp_w, const float* __restrict__ comp_b,
    double* __restrict__ xt)
{
  __shared__ float si[256];
  const int bn = blockIdx.x;
  const int b = bn / NBAR, n = bn % NBAR;
  const int tid = threadIdx.x;
  si[tid] = inp[bn*256 + tid];
  __syncthreads();
  const int c = tid & 63, tq = tid >> 6;
  double wv[6];
  #pragma unroll
  for (int u = 0; u < 6; ++u) wv[u] = (double)comp_w[c*6 + u];
  const double cb = (double)comp_b[c];
  for (int t = tq; t < TSTEPS; t += 4) {
    const int p0 = 2*t - 1;
    double acc = cb;
    if (p0 >= 0) acc += (double)si[p0]     * wv[0];
    acc             += (double)si[p0+1]    * wv[1];
    acc             += (double)si[p0+2]    * wv[2];
    if (p0 >= 0) acc += (double)si[128+p0] * wv[3];
    acc             += (double)si[128+p0+1]* wv[4];
    acc             += (double)si[128+p0+2]* wv[5];
    xt[((t*BATCH + b)*NBAR + n)*CCH + c] = acc;
  }
}

// ---------------- grouped-weight build ----------------
__global__ __launch_bounds__(256) void kprepw(const float* __restrict__ pop_w,
    float* __restrict__ gw)
{
  const int bx = blockIdx.x;          // j*NBAR + n
  const int j = bx / NBAR, n = bx % NBAR;
  const int NT = G_NT[j];
  const int total = NT*1024;
  for (int e = threadIdx.x; e < total; e += 256) {
    const int c = e / (NT*32), r = e % (NT*32), tt = r >> 5, oo = r & 31;
    const int k = G_K[G_CUM[j]+tt];
    gw[G_OFFW[j] + (n*32+c)*NT*32 + tt*32 + oo] = pop_w[k*39936 + n*1024 + oo*32 + c];
  }
  if (n == 0)
    for (int e = threadIdx.x; e < NT*32; e += 256)
      gw[G_OFFW[j] + 1248*NT*32 + e] = 0.0f;   // zero-pad flat slot
}

// ---------------- per-neuron constants + aggT transpose ----------------
__global__ __launch_bounds__(256) void kprepn(const float* __restrict__ th_b,
    const float* __restrict__ pop_b, const float* __restrict__ tau_adp,
    const float* __restrict__ tau_m, const float* __restrict__ agg_w,
    double* __restrict__ cbias, double* __restrict__ alro, float* __restrict__ aggT)
{
  const int e = blockIdx.x*256 + threadIdx.x;
  if (e < 8192) aggT[e] = agg_w[(e & 31)*256 + (e >> 5)];   // [m][o] <- [o][m]
  if (e >= NPOPS*NEUR) return;
  const int i = e / NEUR, r = e % NEUR;
  double cb = (double)th_b[e];
  const int no = C_NSRC[i], ofi = C_OFF[i];
  for (int jj = 0; jj < no; ++jj) cb += (double)pop_b[(ofi+jj)*NEUR + r];
  cbias[e] = cb;
  alro[2*e]   = exp(-1.0/(double)tau_m[e]);
  alro[2*e+1] = exp(-1.0/(double)tau_adp[e]);
}

// ---------------- similarity + top-3 (bank-conflict-free, padded) ----------------
__global__ __launch_bounds__(256) void ksim(const double* __restrict__ xt, int* __restrict__ idxg)
{
  __shared__ double sx[NBAR*65];        // stride 65 f64 -> conflict-free
  __shared__ double simL[NBAR*40];
  const int g = blockIdx.x;             // t*BATCH + b
  const int tid = threadIdx.x;
  const double* base = xt + (size_t)g*NBAR*CCH;
  for (int e = tid; e < NBAR*CCH; e += 256) sx[(e>>6)*65 + (e&63)] = base[e];
  __syncthreads();
  for (int p = tid; p < NBAR*NBAR; p += 256) {
    const int n = p / NBAR, m = p - n*NBAR;
    const double* xn = sx + n*65;
    const double* xm = sx + m*65;
    double acc = 0.0;
    #pragma unroll
    for (int c = 0; c < CCH; ++c) acc += xn[c]*xm[c];
    simL[n*40+m] = acc;
  }
  __syncthreads();
  if (tid < NBAR) {
    const double* row = simL + tid*40;
    double v0=-1e300, v1=-1e300, v2=-1e300; int i0=0, i1=0, i2=0;
    for (int m = 0; m < NBAR; ++m) {
      const double v = row[m];
      if      (v > v0) { v2=v1;i2=i1; v1=v0;i1=i0; v0=v;i0=m; }
      else if (v > v1) { v2=v1;i2=i1; v1=v; i1=m; }
      else if (v > v2) { v2=v; i2=m; }
    }
    int* op = idxg + (g*NBAR + tid)*3;
    op[0]=i0; op[1]=i1; op[2]=i2;
  }
}

// ---------------- drive precompute: register-tiled GEMM per barrel ----------------
__global__ __launch_bounds__(512) void kdrive(const double* __restrict__ xt,
    const float* __restrict__ th_w, const double* __restrict__ cbias,
    double* __restrict__ drive, int c0)
{
  __shared__ double sx[64*64];          // [row][c]   32 KB
  __shared__ float  sw[64*256];         // [c][pop*32+o]  64 KB
  const int n = blockIdx.x % NBAR, sl = blockIdx.x / NBAR;
  const int tid = threadIdx.x;
  for (int e = tid; e < 64*256; e += 512) {
    const int f = e >> 6, c = e & 63;   // f = pop*32+o
    sw[c*256 + f] = th_w[((f>>5)*NBAR + n)*2048 + (f&31)*64 + c];
  }
  for (int e = tid; e < 64*64; e += 512) {
    const int rr = e >> 6, cc = e & 63;
    const int g = sl*64 + rr, tt = g >> 6, bb = g & 63;
    sx[e] = xt[(((size_t)(c0+tt)*BATCH + bb)*NBAR + n)*CCH + cc];
  }
  __syncthreads();
  const int ot = tid & 31, rt = tid >> 5;
  double acc[4][8];
  #pragma unroll
  for (int k = 0; k < 8; ++k) {
    const double cb = cbias[k*NEUR + n*PSZ + ot];
    #pragma unroll
    for (int j = 0; j < 4; ++j) acc[j][k] = cb;
  }
  #pragma unroll 1
  for (int c = 0; c < 64; ++c) {
    double xv[4];
    #pragma unroll
    for (int j = 0; j < 4; ++j) xv[j] = sx[(rt*4+j)*64 + c];
    float wv[8];
    #pragma unroll
    for (int k = 0; k < 8; ++k) wv[k] = sw[c*256 + k*32 + ot];
    #pragma unroll
    for (int j = 0; j < 4; ++j)
      #pragma unroll
      for (int k = 0; k < 8; ++k)
        acc[j][k] += xv[j] * (double)wv[k];
  }
  #pragma unroll
  for (int j = 0; j < 4; ++j)
    #pragma unroll
    for (int k = 0; k < 8; ++k)
      drive[((size_t)(sl*64 + rt*4 + j)*NPOPS + k)*NEUR + n*PSZ + ot] = acc[j][k];
}

// scatter source-J spikes (masks g0,g1) into acc registers, 4+4 bits per wait
template<int J>
__device__ __forceinline__ void scatJ(unsigned g0, unsigned g1, int n0, int n1v,
    const float* __restrict__ gw, int o, double* __restrict__ a0, double* __restrict__ a1)
{
  constexpr int NT = G_NT[J];
  constexpr int CU = G_CUM[J];
  const float* base = gw + G_OFFW[J] + o;
  while (g0 | g1) {
    int f0[4], f1[4];
    #pragma unroll
    for (int u = 0; u < 4; ++u) {
      f0[u] = g0 ? (n0*32  + (__ffs(g0)-1)) : 1248; g0 &= g0-1;
      f1[u] = g1 ? (n1v*32 + (__ffs(g1)-1)) : 1248; g1 &= g1-1;
    }
    float w0[4][NT], w1[4][NT];
    #pragma unroll
    for (int u = 0; u < 4; ++u) {
      const float* p0 = base + (size_t)f0[u]*(NT*32);
      const float* p1 = base + (size_t)f1[u]*(NT*32);
      #pragma unroll
      for (int tt = 0; tt < NT; ++tt) { w0[u][tt]=p0[tt*32]; w1[u][tt]=p1[tt*32]; }
    }
    #pragma unroll
    for (int tt = 0; tt < NT; ++tt) {
      const int tg = G_TGT[CU+tt];
      a0[tg] += (((double)w0[0][tt]+(double)w0[1][tt]) + ((double)w0[2][tt]+(double)w0[3][tt]));
      a1[tg] += (((double)w1[0][tt]+(double)w1[1][tt]) + ((double)w1[2][tt]+(double)w1[3][tt]));
    }
  }
}

// ---------------- recurrent core: 640 thr, 1 raw barrier per pop-step ----------------
// __launch_bounds__(640,3): VGPR cap ~170 (verified R10: reduced spills).
// bbr state lives in LDS (verified R12: -640 MB spill round-trips).
__global__ __launch_bounds__(640, 3) void krec(
    const double* __restrict__ drv, const int* __restrict__ idxg,
    const float* __restrict__ gw, const float* __restrict__ aggTg,
    const float* __restrict__ agg_b, const double* __restrict__ alro,
    double* __restrict__ memG, double* __restrict__ bbrG,
    double* __restrict__ accG, double* __restrict__ stProj, unsigned* __restrict__ stSp,
    float* __restrict__ hOut, float* __restrict__ mOut, int t0, int nT)
{
  __shared__ double   proj[2][NBAR*PSZ];  // 19,968 B ping-pong
  __shared__ float    aggT[256*PSZ];      // 32,768 B
  __shared__ unsigned spM[NPOPS*40];      //  1,280 B
  __shared__ double   bbrL[NPOPS*40*PSZ]; // 81,920 B  ([i][40][32], row 39 dummy)
  const int b = blockIdx.x, tid = threadIdx.x;
  const int o = tid & 31, s = tid >> 5;   // 20 half-wave slots
  const int n0 = s, n1 = s + 20;
  const bool h1 = (n1 < NBAR);            // s < 19
  const int n1v = h1 ? n1 : n0;

  for (int e = tid; e < 256*PSZ; e += 640) aggT[e] = aggTg[e];

  double mem0[NPOPS], mem1[NPOPS], acc0[NPOPS], acc1[NPOPS];
  const size_t mbase = (size_t)b*NPOPS*NEUR;
  if (t0 == 0) {
    #pragma unroll
    for (int i = 0; i < NPOPS; ++i) {
      mem0[i]=0.0; mem1[i]=0.0; acc0[i]=0.0; acc1[i]=0.0;
    }
    for (int e = tid; e < NPOPS*40*PSZ; e += 640) bbrL[e] = 0.0;
    for (int e = tid; e < NBAR*PSZ; e += 640) proj[0][e] = 0.0;
    for (int e = tid; e < NPOPS*40; e += 640) spM[e] = 0u;
  } else {
    #pragma unroll
    for (int i = 0; i < NPOPS; ++i) {
      const size_t eA = mbase + i*NEUR + n0*PSZ + o;
      const size_t eB = mbase + i*NEUR + n1v*PSZ + o;
      mem0[i] = memG[eA]; acc0[i] = accG[eA];
      mem1[i] = h1 ? memG[eB] : 0.0;
      acc1[i] = h1 ? accG[eB] : 0.0;
    }
    for (int e = tid; e < NPOPS*NEUR; e += 640)
      bbrL[(e/NEUR)*1280 + (e%NEUR)] = bbrG[mbase + e];
    if (tid < NPOPS*PSZ) bbrL[(tid>>5)*1280 + 39*PSZ + (tid&31)] = 0.0; // dummy row
    for (int e = tid; e < NBAR*PSZ; e += 640) proj[0][e] = stProj[b*NEUR + e];
    for (int e = tid; e < NPOPS*40; e += 640)
      spM[e] = ((e % 40) < NBAR) ? stSp[b*NPOPS*NBAR + (e/40)*NBAR + (e%40)] : 0u;
  }
  __syncthreads();
  const double aggBo = (double)agg_b[o];
  int rb = 0;

  #pragma unroll 1
  for (int tt = 0; tt < nT; ++tt) {
    const int t = t0 + tt;
    const double* drvT = drv + ((size_t)(tt*BATCH + b))*NPOPS*NEUR;
    #pragma unroll
    for (int i = 0; i < NPOPS; ++i) {
      acc0[i] += drvT[i*NEUR + n0*PSZ + o];
      if (h1) acc1[i] += drvT[i*NEUR + n1*PSZ + o];
    }
    int ia0[3], ia1[3];
    { const int* ip = idxg + ((t*BATCH+b)*NBAR + n0)*3; ia0[0]=ip[0]; ia0[1]=ip[1]; ia0[2]=ip[2]; }
    if (h1) { const int* ip = idxg + ((t*BATCH+b)*NBAR + n1)*3; ia1[0]=ip[0]; ia1[1]=ip[1]; ia1[2]=ip[2]; }
    else    { ia1[0]=ia1[1]=ia1[2]=0; }

    #pragma unroll
    for (int i = 0; i < NPOPS; ++i) {
      const int eA = i*NEUR + n0*PSZ + o;
      const int eB = i*NEUR + n1v*PSZ + o;
      const double al0 = alro[2*eA], ro0 = alro[2*eA+1];
      const double al1 = alro[2*eB], ro1 = alro[2*eB+1];
      const double* prj = proj[rb];
      double*       prw = proj[rb^1];
      const int bix0 = i*1280 + n0*PSZ + o;
      const int bix1 = i*1280 + n1*PSZ + o;   // row 39 dummy for s=19

      // ---- phase 1: fold acc + neighbor agg (reads prj)
      double cur0 = acc0[i]; acc0[i] = 0.0;
      double cur1 = acc1[i]; acc1[i] = 0.0;
      if (t > 0) {
        cur0 += 0.1*((prj[ia0[0]*PSZ+o]+prj[ia0[1]*PSZ+o]+prj[ia0[2]*PSZ+o])/3.0 + aggBo);
        if (h1)
          cur1 += 0.1*((prj[ia1[0]*PSZ+o]+prj[ia1[1]*PSZ+o]+prj[ia1[2]*PSZ+o])/3.0 + aggBo);
      }

      // ---- phase 2: neuron update, ballot, outputs, proj copy+delta (writes prw)
      unsigned newM0, newM1;
      {
        const unsigned oldM = spM[i*40 + n0];
        const double sOld = (double)((oldM >> o) & 1u);
        const double bn  = ro0*bbrL[bix0] + (1.0-ro0)*sOld;
        const double Bth = 0.02 + 1.8*bn;
        const double mN  = mem0[i]*al0 + (1.0-al0)*cur0;
        const int spk = (mN - Bth) > 0.0;
        mem0[i] = mN - Bth*(double)spk;
        bbrL[bix0] = bn;
        const int ob = ((b*TSTEPS + t)*NBAR + n0)*256 + i*PSZ + o;
        hOut[ob] = (float)spk;
        mOut[ob] = (float)mN;
        const unsigned long long bal = __ballot(spk);
        newM0 = (tid & 32) ? (unsigned)(bal >> 32) : (unsigned)(bal & 0xffffffffULL);
        if (o == 0) spM[i*40 + n0] = newM0;
        unsigned diff = newM0 ^ oldM;
        double pv = prj[n0*PSZ + o];
        while (diff) {
          unsigned d = diff;
          const int cA = __ffs(d)-1; d &= d-1;
          const bool hB = d!=0; const int cB = hB ? __ffs(d)-1 : cA; d &= d-1;
          const bool hC = d!=0; const int cC = hC ? __ffs(d)-1 : cA; d &= d-1;
          const bool hD = d!=0; const int cD = hD ? __ffs(d)-1 : cA; d &= d-1;
          diff = d;
          const double wA = (double)aggT[(i*PSZ+cA)*PSZ+o];
          const double wB = (double)aggT[(i*PSZ+cB)*PSZ+o];
          const double wC = (double)aggT[(i*PSZ+cC)*PSZ+o];
          const double wD = (double)aggT[(i*PSZ+cD)*PSZ+o];
          pv += ((newM0>>cA)&1u) ? wA : -wA;
          pv += hB ? (((newM0>>cB)&1u) ? wB : -wB) : 0.0;
          pv += hC ? (((newM0>>cC)&1u) ? wC : -wC) : 0.0;
          pv += hD ? (((newM0>>cD)&1u) ? wD : -wD) : 0.0;
        }
        prw[n0*PSZ + o] = pv;
      }
      {
        const unsigned oldM = h1 ? spM[i*40 + n1] : 0u;
        const double sOld = (double)((oldM >> o) & 1u);
        const double bn  = ro1*bbrL[bix1] + (1.0-ro1)*sOld;
        const double Bth = 0.02 + 1.8*bn;
        const double mN  = mem1[i]*al1 + (1.0-al1)*cur1;
        const int spk = (mN - Bth) > 0.0;
        mem1[i] = mN - Bth*(double)spk;
        bbrL[bix1] = bn;
        if (h1) {
          const int ob = ((b*TSTEPS + t)*NBAR + n1)*256 + i*PSZ + o;
          hOut[ob] = (float)spk;
          mOut[ob] = (float)mN;
        }
        const unsigned long long bal = __ballot(h1 && spk);
        newM1 = (tid & 32) ? (unsigned)(bal >> 32) : (unsigned)(bal & 0xffffffffULL);
        if (h1) {
          if (o == 0) spM[i*40 + n1] = newM1;
          unsigned diff = newM1 ^ oldM;
          double pv = prj[n1*PSZ + o];
          while (diff) {
            unsigned d = diff;
            const int cA = __ffs(d)-1; d &= d-1;
            const bool hB = d!=0; const int cB = hB ? __ffs(d)-1 : cA; d &= d-1;
            const bool hC = d!=0; const int cC = hC ? __ffs(d)-1 : cA; d &= d-1;
            const bool hD = d!=0; const int cD = hD ? __ffs(d)-1 : cA; d &= d-1;
            diff = d;
            const double wA = (double)aggT[(i*PSZ+cA)*PSZ+o];
            const double wB = (double)aggT[(i*PSZ+cB)*PSZ+o];
            const double wC = (double)aggT[(i*PSZ+cC)*PSZ+o];
            const double wD = (double)aggT[(i*PSZ+cD)*PSZ+o];
            pv += ((newM1>>cA)&1u) ? wA : -wA;
            pv += hB ? (((newM1>>cB)&1u) ? wB : -wB) : 0.0;
            pv += hC ? (((newM1>>cC)&1u) ? wC : -wC) : 0.0;
            pv += hD ? (((newM1>>cD)&1u) ? wD : -wD) : 0.0;
          }
          prw[n1*PSZ + o] = pv;
        }
      }

      // ---- scatter source-i spikes into acc regs (loads drain lazily, next steps)
      const unsigned g0 = newM0, g1 = h1 ? newM1 : 0u;
      if      (i == 0) scatJ<0>(g0, g1, n0, n1v, gw, o, acc0, acc1);
      else if (i == 1) scatJ<1>(g0, g1, n0, n1v, gw, o, acc0, acc1);
      else if (i == 2) scatJ<2>(g0, g1, n0, n1v, gw, o, acc0, acc1);
      else if (i == 3) scatJ<3>(g0, g1, n0, n1v, gw, o, acc0, acc1);
      else if (i == 4) scatJ<4>(g0, g1, n0, n1v, gw, o, acc0, acc1);
      else if (i == 5) scatJ<5>(g0, g1, n0, n1v, gw, o, acc0, acc1);
      else if (i == 6) scatJ<6>(g0, g1, n0, n1v, gw, o, acc0, acc1);
      else             scatJ<7>(g0, g1, n0, n1v, gw, o, acc0, acc1);

      STEP_BAR();      // lgkmcnt(0) + s_barrier only; vmem stays in flight
      rb ^= 1;
    }
  }

  // persist chunk state only when another chunk follows
  if (t0 + nT < TSTEPS) {
    #pragma unroll
    for (int i = 0; i < NPOPS; ++i) {
      const size_t eA = mbase + i*NEUR + n0*PSZ + o;
      memG[eA] = mem0[i]; accG[eA] = acc0[i];
      if (h1) {
        const size_t eB = mbase + i*NEUR + n1*PSZ + o;
        memG[eB] = mem1[i]; accG[eB] = acc1[i];
      }
    }
    for (int e = tid; e < NPOPS*NEUR; e += 640)
      bbrG[mbase + e] = bbrL[(e/NEUR)*1280 + (e%NEUR)];
    for (int e = tid; e < NEUR; e += 640) stProj[b*NEUR + e] = proj[rb][e];
    for (int e = tid; e < NPOPS*NBAR; e += 640)
      stSp[b*NPOPS*NBAR + e] = spM[(e/NBAR)*40 + (e%NBAR)];
  }
}

// ---------------- readout ----------------
__global__ __launch_bounds__(256) void kread(const float* __restrict__ hBase,
    const float* __restrict__ ro_w, const float* __restrict__ ro_b, float* __restrict__ outp)
{
  __shared__ double part[2][128];
  __shared__ double meanv[128];
  __shared__ double lg[36];
  const int b = blockIdx.x, tid = threadIdx.x;
  const int d = tid & 127, half = tid >> 7;
  double acc = 0.0;
  for (int r = half*1248; r < half*1248 + 1248; ++r)
    acc += (double)hBase[((size_t)b*2496 + r)*256 + 128 + d];
  part[half][d] = acc;
  __syncthreads();
  if (tid < 128) meanv[tid] = (part[0][tid] + part[1][tid]) / 2496.0;
  __syncthreads();
  if (tid < 36) {
    double a = (double)ro_b[tid];
    for (int e = 0; e < 128; ++e) a += meanv[e]*(double)ro_w[tid*128 + e];
    lg[tid] = a;
  }
  __syncthreads();
  if (tid == 0) {
    double mx = lg[0];
    for (int dd = 1; dd < 36; ++dd) mx = fmax(mx, lg[dd]);
    double ex[36]; double sum = 0.0;
    for (int dd = 0; dd < 36; ++dd) { ex[dd] = exp(lg[dd]-mx); sum += ex[dd]; }
    for (int dd = 0; dd < 36; ++dd) outp[b*36 + dd] = (float)(ex[dd]/sum);
  }
}

// ---------------- launcher ----------------
extern "C" void kernel_launch(void* const* d_in, const int* in_sizes, int n_in,
                              void* d_out, int out_size, void* d_ws, size_t ws_size,
                              hipStream_t stream)
{
  const float* inp     = (const float*)d_in[0];
  const float* comp_w  = (const float*)d_in[1];
  const float* comp_b  = (const float*)d_in[2];
  const float* th_w    = (const float*)d_in[3];
  const float* th_b    = (const float*)d_in[4];
  const float* pop_w   = (const float*)d_in[5];
  const float* pop_b   = (const float*)d_in[6];
  const float* tau_adp = (const float*)d_in[7];
  const float* tau_m   = (const float*)d_in[8];
  const float* agg_w   = (const float*)d_in[9];
  const float* agg_b   = (const float*)d_in[10];
  const float* ro_w    = (const float*)d_in[11];
  const float* ro_b    = (const float*)d_in[12];

  char* ws = (char*)d_ws;
  float* outp = (float*)d_out;                 // (64,36) softmax
  float* hOut = outp + 64*36;                  // (64,64,39,256)
  float* mOut = hOut + 64*64*39*256;           // (64,64,39,256)

  const bool full = (ws_size >= FU_END);

  if (full) {
    // -------- full path: drive for all 64 t, single krec launch --------
    double*   xt     = (double*)  (ws + FU_XT);
    double*   drive  = (double*)  (ws + FU_DRIVE);
    int*      idxg   = (int*)     (ws + FU_IDX);
    float*    gw     = (float*)   (ws + FU_GW);
    float*    aggT   = (float*)   (ws + FU_AGGT);
    double*   cbias  = (double*)  (ws + FU_CBIAS);
    double*   alro   = (double*)  (ws + FU_ALRO);
    double*   dummy  = (double*)  (ws + FU_XT);    // state ptrs never touched (t0=0, nT=64)
    unsigned* dummyu = (unsigned*)(ws + FU_XT);

    kconv <<<BATCH*NBAR, 256, 0, stream>>>(inp, comp_w, comp_b, xt);
    kprepw<<<NPOPS*NBAR, 256, 0, stream>>>(pop_w, gw);
    kprepn<<<39, 256, 0, stream>>>(th_b, pop_b, tau_adp, tau_m, agg_w, cbias, alro, aggT);
    ksim  <<<TSTEPS*BATCH, 256, 0, stream>>>(xt, idxg);
    kdrive<<<NBAR*64, 512, 0, stream>>>(xt, th_w, cbias, drive, 0);
    krec  <<<BATCH, 640, 0, stream>>>(drive, idxg, gw, aggT, agg_b, alro,
                                      dummy, dummy, dummy, dummy, dummyu,
                                      hOut, mOut, 0, TSTEPS);
    kread <<<BATCH, 256, 0, stream>>>(hOut, ro_w, ro_b, outp);
  } else {
    // -------- fallback: chunked path --------
    double*   xt     = (double*)  (ws + FB_XT);
    double*   drive  = (double*)  (ws + FB_DRIVE);
    int*      idxg   = (int*)     (ws + FB_IDX);
    float*    gw     = (float*)   (ws + FB_GW);
    float*    aggT   = (float*)   (ws + FB_AGGT);
    double*   cbias  = (double*)  (ws + FB_CBIAS);
    double*   alro   = (double*)  (ws + FB_ALRO);
    double*   memG   = (double*)  (ws + FB_MEMG);
    double*   bbrG   = (double*)  (ws + FB_BBRG);
    double*   accG   = (double*)  (ws + FB_ACCG);
    double*   stProj = (double*)  (ws + FB_STPROJ);
    unsigned* stSp   = (unsigned*)(ws + FB_STSP);

    kconv <<<BATCH*NBAR, 256, 0, stream>>>(inp, comp_w, comp_b, xt);
    kprepw<<<NPOPS*NBAR, 256, 0, stream>>>(pop_w, gw);
    kprepn<<<39, 256, 0, stream>>>(th_b, pop_b, tau_adp, tau_m, agg_w, cbias, alro, aggT);
    ksim  <<<TSTEPS*BATCH, 256, 0, stream>>>(xt, idxg);
    for (int c0 = 0; c0 < TSTEPS; c0 += TCH) {
      kdrive<<<NBAR*8, 512, 0, stream>>>(xt, th_w, cbias, drive, c0);
      krec  <<<BATCH, 640, 0, stream>>>(drive, idxg, gw, aggT, agg_b, alro,
                                        memG, bbrG, accG, stProj, stSp,
                                        hOut, mOut, c0, TCH);
    }
    kread <<<BATCH, 256, 0, stream>>>(hOut, ro_w, ro_b, outp);
  }
}